// Round 9
// baseline (481.657 us; speedup 1.0000x reference)
//
#include <hip/hip_runtime.h>
#include <hip/hip_bf16.h>

// Problem constants
#define B_  2
#define S_  2048
#define D_  1024
#define H_  16
#define DK_ 64
#define M_  4096   // B_*S_

using bf16x8 = __attribute__((ext_vector_type(8))) __bf16;
using f32x4  = __attribute__((ext_vector_type(4))) float;

typedef __attribute__((address_space(1))) void gvoid;
typedef __attribute__((address_space(3))) void lvoid;

// async global->LDS, 16B per lane, dest = wave-uniform base + lane*16
__device__ __forceinline__ void gload_lds16(const void* g, void* l) {
  __builtin_amdgcn_global_load_lds((gvoid*)g, (lvoid*)l, 16, 0, 0);
}

__device__ __forceinline__ f32x4 mfma16(bf16x8 a, bf16x8 b, f32x4 c) {
  return __builtin_amdgcn_mfma_f32_16x16x32_bf16(a, b, c, 0, 0, 0);
}

// 64-col bf16 tile: logical (row, col-elem ce) -> swizzled element index.
__device__ __forceinline__ int swz64(int row, int ce) {
  return row * 64 + ((((ce >> 3) ^ (row & 7)) << 3) | (ce & 7));
}

// ---------------------------------------------------------------------------
// LayerNorm (torch variant: unbiased std ddof=1, eps added to std) for the 3
// streams; writes bf16 (GEMM operand) and, for v, also f32 (exact residual).
// grid (4096, 3), block 256, one row per block.
// ---------------------------------------------------------------------------
__global__ __launch_bounds__(256) void ln3_kernel(
    const float* __restrict__ kin, const float* __restrict__ qin,
    const float* __restrict__ vin,
    const float* __restrict__ a2, const float* __restrict__ b2,
    __hip_bfloat16* __restrict__ kn, __hip_bfloat16* __restrict__ qn,
    __hip_bfloat16* __restrict__ vnb, float* __restrict__ vnf)
{
  const int row = blockIdx.x;
  const int st  = blockIdx.y;
  const float* src = (st == 0) ? kin : (st == 1) ? qin : vin;
  const int t = threadIdx.x;
  const size_t base = (size_t)row * D_;

  float4 x = *(const float4*)(src + base + t * 4);
  float s  = x.x + x.y + x.z + x.w;
  float s2 = x.x * x.x + x.y * x.y + x.z * x.z + x.w * x.w;
  #pragma unroll
  for (int off = 32; off >= 1; off >>= 1) {
    s  += __shfl_down(s,  off, 64);
    s2 += __shfl_down(s2, off, 64);
  }
  __shared__ float red[4][2];
  __shared__ float stats[2];
  const int wid = t >> 6, lane = t & 63;
  if (lane == 0) { red[wid][0] = s; red[wid][1] = s2; }
  __syncthreads();
  if (t == 0) {
    float S  = red[0][0] + red[1][0] + red[2][0] + red[3][0];
    float S2 = red[0][1] + red[1][1] + red[2][1] + red[3][1];
    float mean = S * (1.0f / D_);
    float var  = fmaxf((S2 - S * mean) * (1.0f / (D_ - 1)), 0.0f);
    stats[0] = mean;
    stats[1] = 1.0f / (sqrtf(var) + 1e-6f);   // eps added to std
  }
  __syncthreads();
  const float mean = stats[0], inv = stats[1];
  float4 ga = *(const float4*)(a2 + t * 4);
  float4 gb = *(const float4*)(b2 + t * 4);
  float o0 = ga.x * (x.x - mean) * inv + gb.x;
  float o1 = ga.y * (x.y - mean) * inv + gb.y;
  float o2 = ga.z * (x.z - mean) * inv + gb.z;
  float o3 = ga.w * (x.w - mean) * inv + gb.w;
  __hip_bfloat16* dst = (st == 0) ? kn : (st == 1) ? qn : vnb;
  union { __hip_bfloat16 h[4]; ushort4 u; } pk;
  pk.h[0] = __float2bfloat16(o0); pk.h[1] = __float2bfloat16(o1);
  pk.h[2] = __float2bfloat16(o2); pk.h[3] = __float2bfloat16(o3);
  *reinterpret_cast<ushort4*>((unsigned short*)dst + base + t * 4) = pk.u;
  if (st == 2) {
    float4 of = make_float4(o0, o1, o2, o3);
    *reinterpret_cast<float4*>(vnf + base + t * 4) = of;
  }
}

// ---------------------------------------------------------------------------
// Pack mask int32[B,S,S] -> bits u32[B,S,S/32]. grid 1024, block 256.
// ---------------------------------------------------------------------------
__global__ __launch_bounds__(256) void pack_mask_kernel(
    const int* __restrict__ mask, unsigned int* __restrict__ bits)
{
  const int w = blockIdx.x * 256 + threadIdx.x;     // B*S*(S/32) = 262144
  const int* src = mask + (size_t)w * 32;
  unsigned int acc = 0;
  #pragma unroll
  for (int j = 0; j < 32; j += 4) {
    int4 t = *(const int4*)(src + j);
    acc |= (t.x != 0 ? 1u : 0u) << (j + 0);
    acc |= (t.y != 0 ? 1u : 0u) << (j + 1);
    acc |= (t.z != 0 ? 1u : 0u) << (j + 2);
    acc |= (t.w != 0 ? 1u : 0u) << (j + 3);
  }
  bits[w] = acc;
}

// ---------------------------------------------------------------------------
// Weight transpose + cast: W f32[K][N] -> Wt bf16[N][K]. grid (32,32,4).
// ---------------------------------------------------------------------------
__global__ __launch_bounds__(256) void wt_cast_kernel(
    const float* __restrict__ W0, const float* __restrict__ W1,
    const float* __restrict__ W2, const float* __restrict__ W3,
    __hip_bfloat16* __restrict__ T0, __hip_bfloat16* __restrict__ T1,
    __hip_bfloat16* __restrict__ T2, __hip_bfloat16* __restrict__ T3)
{
  const int z = blockIdx.z;
  const float* W = (z == 0) ? W0 : (z == 1) ? W1 : (z == 2) ? W2 : W3;
  __hip_bfloat16* T = (z == 0) ? T0 : (z == 1) ? T1 : (z == 2) ? T2 : T3;
  __shared__ float tile[32][33];
  const int k0 = blockIdx.y * 32, n0 = blockIdx.x * 32;
  const int tx = threadIdx.x & 31, ty = threadIdx.x >> 5;
  #pragma unroll
  for (int i = ty; i < 32; i += 8)
    tile[i][tx] = W[(size_t)(k0 + i) * D_ + n0 + tx];
  __syncthreads();
  #pragma unroll
  for (int i = ty; i < 32; i += 8)
    T[(size_t)(n0 + i) * D_ + k0 + tx] = __float2bfloat16(tile[tx][i]);
}

// ---------------------------------------------------------------------------
// Batched projection GEMM: z=0: Qb=(LN(k)@Wq+bq)*0.125*log2(e) -> [B,H,S,DK]
//                          z=1: Kb= LN(q)@Wk+bk               -> [B,H,S,DK]
//                          z=2: Vtb=LN(v)@Wv+bv               -> [B,H,DK,S]
// 128x128 tile, BK=32, 4 waves (2x2). grid (8, 32, 3), block 256.
// ---------------------------------------------------------------------------
__global__ __launch_bounds__(256) void proj3_kernel(
    const __hip_bfloat16* __restrict__ kn, const __hip_bfloat16* __restrict__ qn,
    const __hip_bfloat16* __restrict__ vnb,
    const __hip_bfloat16* __restrict__ Wqt, const __hip_bfloat16* __restrict__ Wkt,
    const __hip_bfloat16* __restrict__ Wvt,
    const float* __restrict__ bq, const float* __restrict__ bk,
    const float* __restrict__ bv,
    __hip_bfloat16* __restrict__ Qb, __hip_bfloat16* __restrict__ Kb,
    __hip_bfloat16* __restrict__ Vtb)
{
  const int z = blockIdx.z;
  const __hip_bfloat16* A  = (z == 0) ? kn  : (z == 1) ? qn  : vnb;
  const __hip_bfloat16* Wt = (z == 0) ? Wqt : (z == 1) ? Wkt : Wvt;
  const float* bias = (z == 0) ? bq : (z == 1) ? bk : bv;
  // fold 1/sqrt(dk) AND log2(e) into Q so attn softmax uses exp2 directly
  const float scale = (z == 0) ? 0.125f * 1.44269504088896340736f : 1.0f;

  __shared__ __hip_bfloat16 As[128 * 32];
  __shared__ __hip_bfloat16 Bs[128 * 32];
  const int n0 = blockIdx.x * 128;
  const int m0 = blockIdx.y * 128;
  const int tid = threadIdx.x;
  const int wid = tid >> 6, lane = tid & 63;
  const int wm = wid >> 1, wn = wid & 1;
  const int srow = lane >> 2;            // staging: 4 lanes per 64B row
  const int scol = (lane & 3) * 8;
  const int fr = lane & 15, fk8 = (lane >> 4) * 8, fq = lane >> 4;

  f32x4 acc[4][4] = {};

  for (int kt = 0; kt < D_ / 32; ++kt) {
    const int k0 = kt * 32;
    #pragma unroll
    for (int p = 0; p < 2; ++p) {
      const int r0 = 32 * wid + 16 * p;
      gload_lds16(A  + (size_t)(m0 + r0 + srow) * D_ + k0 + scol, &As[r0 * 32]);
      gload_lds16(Wt + (size_t)(n0 + r0 + srow) * D_ + k0 + scol, &Bs[r0 * 32]);
    }
    __syncthreads();
    bf16x8 af[4], bfr[4];
    #pragma unroll
    for (int i = 0; i < 4; ++i)
      af[i] = *(const bf16x8*)&As[(64 * wm + 16 * i + fr) * 32 + fk8];
    #pragma unroll
    for (int j = 0; j < 4; ++j)
      bfr[j] = *(const bf16x8*)&Bs[(64 * wn + 16 * j + fr) * 32 + fk8];
    #pragma unroll
    for (int i = 0; i < 4; ++i)
      #pragma unroll
      for (int j = 0; j < 4; ++j)
        acc[i][j] = mfma16(af[i], bfr[j], acc[i][j]);
    __syncthreads();
  }

  // Epilogue. row m = m0+64*wm+16*i+4*fq+r, col n = n0+64*wn+16*j+fr
  #pragma unroll
  for (int i = 0; i < 4; ++i) {
    #pragma unroll
    for (int j = 0; j < 4; ++j) {
      const int n = n0 + 64 * wn + 16 * j + fr;
      const float bn = bias[n];
      const int h = n >> 6, d = n & (DK_ - 1);
      #pragma unroll
      for (int r = 0; r < 4; ++r) {
        const int m = m0 + 64 * wm + 16 * i + 4 * fq + r;
        const int b = m >> 11, sl = m & (S_ - 1);
        const float val = (acc[i][j][r] + bn) * scale;
        if (z < 2) {
          __hip_bfloat16* dst = (z == 0) ? Qb : Kb;
          dst[((size_t)(b * H_ + h) * S_ + sl) * DK_ + d] = __float2bfloat16(val);
        } else {
          Vtb[((size_t)(b * H_ + h) * DK_ + d) * S_ + sl] = __float2bfloat16(val);
        }
      }
    }
  }
}

// ---------------------------------------------------------------------------
// Output GEMM: out f32[M][D] = Ob @ Wot^T + bo + vnf. grid (8, 32), block 256.
// ---------------------------------------------------------------------------
__global__ __launch_bounds__(256) void gemm_out_kernel(
    const __hip_bfloat16* __restrict__ A,
    const __hip_bfloat16* __restrict__ Wt,
    const float* __restrict__ bias,
    const float* __restrict__ residf,
    float* __restrict__ dst)
{
  __shared__ __hip_bfloat16 As[128 * 32];
  __shared__ __hip_bfloat16 Bs[128 * 32];
  const int n0 = blockIdx.x * 128;
  const int m0 = blockIdx.y * 128;
  const int tid = threadIdx.x;
  const int wid = tid >> 6, lane = tid & 63;
  const int wm = wid >> 1, wn = wid & 1;
  const int srow = lane >> 2;
  const int scol = (lane & 3) * 8;
  const int fr = lane & 15, fk8 = (lane >> 4) * 8, fq = lane >> 4;

  f32x4 acc[4][4] = {};

  for (int kt = 0; kt < D_ / 32; ++kt) {
    const int k0 = kt * 32;
    #pragma unroll
    for (int p = 0; p < 2; ++p) {
      const int r0 = 32 * wid + 16 * p;
      gload_lds16(A  + (size_t)(m0 + r0 + srow) * D_ + k0 + scol, &As[r0 * 32]);
      gload_lds16(Wt + (size_t)(n0 + r0 + srow) * D_ + k0 + scol, &Bs[r0 * 32]);
    }
    __syncthreads();
    bf16x8 af[4], bfr[4];
    #pragma unroll
    for (int i = 0; i < 4; ++i)
      af[i] = *(const bf16x8*)&As[(64 * wm + 16 * i + fr) * 32 + fk8];
    #pragma unroll
    for (int j = 0; j < 4; ++j)
      bfr[j] = *(const bf16x8*)&Bs[(64 * wn + 16 * j + fr) * 32 + fk8];
    #pragma unroll
    for (int i = 0; i < 4; ++i)
      #pragma unroll
      for (int j = 0; j < 4; ++j)
        acc[i][j] = mfma16(af[i], bfr[j], acc[i][j]);
    __syncthreads();
  }

  #pragma unroll
  for (int i = 0; i < 4; ++i) {
    #pragma unroll
    for (int j = 0; j < 4; ++j) {
      const int n = n0 + 64 * wn + 16 * j + fr;
      const float bn = bias[n];
      #pragma unroll
      for (int r = 0; r < 4; ++r) {
        const int m = m0 + 64 * wm + 16 * i + 4 * fq + r;
        dst[(size_t)m * D_ + n] =
            acc[i][j][r] + bn + residf[(size_t)m * D_ + n];
      }
    }
  }
}

// ---------------------------------------------------------------------------
// Flash attention, zero-barrier K-loop. K/V per (b,h) = 512 KB -> L2-resident
// (Common-mistake #7: don't LDS-stage L2-fit data). MFMA B-fragments of both
// K ([S,DK] rows) and V ([DK,S] rows) are 16B-contiguous, so fragments load
// DIRECTLY global->VGPR; Q lives in registers (loaded once). Only the per-wave
// P buffer stays in LDS (wave-internal lgkmcnt ordering - no __syncthreads in
// the loop). Q pre-scaled by 0.125*log2(e): softmax p = exp2(s), fixed shift
// m=0 (LN'd inputs: |s| ~ N(0,1), overflow needs 88 sigma).
// block = (q-tile of 64, b*H+h), 4 waves x 16 q-rows, KVBLK=64. grid (32,32).
// ---------------------------------------------------------------------------
__global__ __launch_bounds__(256) void attn_kernel(
    const __hip_bfloat16* __restrict__ Qb,   // [B,H,S,DK], pre-scaled
    const __hip_bfloat16* __restrict__ Kb,   // [B,H,S,DK]
    const __hip_bfloat16* __restrict__ Vtb,  // [B,H,DK,S]
    const unsigned int* __restrict__ mbits,  // [B,S,S/32]
    __hip_bfloat16* __restrict__ Ob)         // [B,S,D] row-major
{
  __shared__ __hip_bfloat16 Ps[4][16 * 64];  // per-wave P, swizzled

  const int q0 = blockIdx.x * 64;
  const int bh = blockIdx.y;
  const int b = bh >> 4;
  const int h = bh & 15;
  const int tid = threadIdx.x, wid = tid >> 6, lane = tid & 63;
  const __hip_bfloat16* qp = Qb  + (size_t)bh * S_ * DK_;
  const __hip_bfloat16* kp = Kb  + (size_t)bh * S_ * DK_;
  const __hip_bfloat16* vp = Vtb + (size_t)bh * DK_ * S_;

  const int fr = lane & 15, fq = lane >> 4, fk8 = fq * 8;

  // per-lane mask base: rows q0 + 16*wid + 4*fq + r
  const unsigned int* mrow = mbits + (size_t)b * S_ * (S_ / 32)
                           + (size_t)(q0 + 16 * wid + 4 * fq) * (S_ / 32);

  // Q fragments once: rows q0+16*wid+fr, k-slices ks*32+fk8
  bf16x8 aq[2];
  #pragma unroll
  for (int ks = 0; ks < 2; ++ks)
    aq[ks] = *(const bf16x8*)(qp + (size_t)(q0 + 16 * wid + fr) * DK_
                                 + ks * 32 + fk8);

  float lrun[4] = {0.0f, 0.0f, 0.0f, 0.0f};
  f32x4 acc[4] = {};

  for (int kt = 0; kt < S_ / 64; ++kt) {
    const int k0 = kt * 64;

    // ---- K fragments direct from global (L2-hit after first q-tile)
    bf16x8 kf[2][4];
    #pragma unroll
    for (int ks = 0; ks < 2; ++ks)
      #pragma unroll
      for (int ni = 0; ni < 4; ++ni)
        kf[ks][ni] = *(const bf16x8*)(kp + (size_t)(k0 + 16 * ni + fr) * DK_
                                         + ks * 32 + fk8);

    // ---- QK^T (scale+log2e pre-folded into Q)
    f32x4 sf[4] = {};
    __builtin_amdgcn_s_setprio(1);
    #pragma unroll
    for (int ks = 0; ks < 2; ++ks)
      #pragma unroll
      for (int ni = 0; ni < 4; ++ni)
        sf[ni] = mfma16(aq[ks], kf[ks][ni], sf[ni]);
    __builtin_amdgcn_s_setprio(0);

    // ---- V fragments issue early (latency hides under softmax)
    bf16x8 vf[2][4];
    #pragma unroll
    for (int ks = 0; ks < 2; ++ks)
      #pragma unroll
      for (int di = 0; di < 4; ++di)
        vf[ks][di] = *(const bf16x8*)(vp + (size_t)(16 * di + fr) * S_
                                         + k0 + ks * 32 + fk8);

    // ---- mask + exp2 (fixed shift) + lane-local sum + P write
    // D-layout: col = 16*ni + fr, row = 4*fq + r
    unsigned int wm0[4], wm1[4];
    #pragma unroll
    for (int r = 0; r < 4; ++r) {
      wm0[r] = mrow[(size_t)r * (S_ / 32) + 2 * kt];
      wm1[r] = mrow[(size_t)r * (S_ / 32) + 2 * kt + 1];
    }
    #pragma unroll
    for (int ni = 0; ni < 4; ++ni) {
      const int c = 16 * ni + fr;
      #pragma unroll
      for (int r = 0; r < 4; ++r) {
        float p = exp2f(sf[ni][r]);
        const unsigned int bit = (((c < 32) ? wm0[r] : wm1[r]) >> (c & 31)) & 1u;
        p = bit ? p : 0.0f;
        lrun[r] += p;
        Ps[wid][swz64(4 * fq + r, c)] = __float2bfloat16(p);
      }
    }

    // ---- PV: acc[q][d] += P[q][kloc] V[kloc][d]
    __builtin_amdgcn_s_setprio(1);
    #pragma unroll
    for (int ks = 0; ks < 2; ++ks) {
      const bf16x8 ap = *(const bf16x8*)&Ps[wid][swz64(fr, ks * 32 + fk8)];
      #pragma unroll
      for (int di = 0; di < 4; ++di)
        acc[di] = mfma16(ap, vf[ks][di], acc[di]);
    }
    __builtin_amdgcn_s_setprio(0);
    // no barrier: Ps is per-wave, global K/V are read-only
  }

  // ---- epilogue: reduce row-sums across the 16 fr lanes, then O = acc / l
  #pragma unroll
  for (int off = 1; off < 16; off <<= 1)
    #pragma unroll
    for (int r = 0; r < 4; ++r)
      lrun[r] += __shfl_xor(lrun[r], off, 64);

  #pragma unroll
  for (int di = 0; di < 4; ++di)
    #pragma unroll
    for (int r = 0; r < 4; ++r) {
      const int qg = q0 + 16 * wid + 4 * fq + r;
      Ob[((size_t)b * S_ + qg) * D_ + h * DK_ + 16 * di + fr] =
          __float2bfloat16(acc[di][r] / lrun[r]);
    }
}

// ---------------------------------------------------------------------------
extern "C" void kernel_launch(void* const* d_in, const int* in_sizes, int n_in,
                              void* d_out, int out_size, void* d_ws, size_t ws_size,
                              hipStream_t stream)
{
  const float* k    = (const float*)d_in[0];
  const float* q    = (const float*)d_in[1];
  const float* v    = (const float*)d_in[2];
  const int*   mask = (const int*)  d_in[3];
  const float* Wq   = (const float*)d_in[4];
  const float* bq   = (const float*)d_in[5];
  const float* Wk   = (const float*)d_in[6];
  const float* bk   = (const float*)d_in[7];
  const float* Wv   = (const float*)d_in[8];
  const float* bv   = (const float*)d_in[9];
  const float* Wo   = (const float*)d_in[10];
  const float* bo   = (const float*)d_in[11];
  const float* a2   = (const float*)d_in[12];
  const float* b2   = (const float*)d_in[13];

  char* ws = (char*)d_ws;
  const size_t MB = (size_t)1 << 20;
  __hip_bfloat16* kn   = (__hip_bfloat16*)(ws + 0 * MB);   // 8 MiB  LN(k) bf16
  __hip_bfloat16* qn   = (__hip_bfloat16*)(ws + 8 * MB);   // 8 MiB  LN(q) bf16
  __hip_bfloat16* vnb  = (__hip_bfloat16*)(ws + 16 * MB);  // 8 MiB  LN(v) bf16
  __hip_bfloat16* Wqt  = (__hip_bfloat16*)(ws + 24 * MB);  // 2 MiB
  __hip_bfloat16* Wkt  = (__hip_bfloat16*)(ws + 26 * MB);  // 2 MiB
  __hip_bfloat16* Wvt  = (__hip_bfloat16*)(ws + 28 * MB);  // 2 MiB
  __hip_bfloat16* Wot  = (__hip_bfloat16*)(ws + 30 * MB);  // 2 MiB
  __hip_bfloat16* Qb   = (__hip_bfloat16*)(ws + 32 * MB);  // 8 MiB  [B,H,S,DK]
  __hip_bfloat16* Kb   = (__hip_bfloat16*)(ws + 40 * MB);  // 8 MiB  [B,H,S,DK]
  __hip_bfloat16* Vtb  = (__hip_bfloat16*)(ws + 48 * MB);  // 8 MiB  [B,H,DK,S]
  __hip_bfloat16* Ob   = (__hip_bfloat16*)(ws + 56 * MB);  // 8 MiB  [M,D]
  unsigned int*   mbts = (unsigned int*)  (ws + 64 * MB);  // 2 MiB  mask bits
  float*          vnf  = (float*)         (ws + 66 * MB);  // 16 MiB LN(v) f32

  ln3_kernel<<<dim3(M_, 3), 256, 0, stream>>>(k, q, v, a2, b2, kn, qn, vnb, vnf);
  pack_mask_kernel<<<dim3(B_ * S_ * (S_ / 32) / 256), 256, 0, stream>>>(mask, mbts);
  wt_cast_kernel<<<dim3(32, 32, 4), 256, 0, stream>>>(Wq, Wk, Wv, Wo, Wqt, Wkt, Wvt, Wot);

  // Reference quirk: query = LN(k)@Wq, key = LN(q)@Wk, value = LN(v)@Wv
  proj3_kernel<<<dim3(8, 32, 3), 256, 0, stream>>>(
      kn, qn, vnb, Wqt, Wkt, Wvt, bq, bk, bv, Qb, Kb, Vtb);

  attn_kernel<<<dim3(S_ / 64, B_ * H_), 256, 0, stream>>>(Qb, Kb, Vtb, mbts, Ob);

  gemm_out_kernel<<<dim3(8, 32), 256, 0, stream>>>(Ob, Wot, bo, vnf, (float*)d_out);
}

// Round 12
// 325.542 us; speedup vs baseline: 1.4796x; 1.4796x over previous
//
#include <hip/hip_runtime.h>
#include <hip/hip_bf16.h>

// Problem constants
#define B_  2
#define S_  2048
#define D_  1024
#define H_  16
#define DK_ 64
#define M_  4096   // B_*S_

using bf16x8 = __attribute__((ext_vector_type(8))) __bf16;
using f32x4  = __attribute__((ext_vector_type(4))) float;

typedef __attribute__((address_space(1))) void gvoid;
typedef __attribute__((address_space(3))) void lvoid;

// async global->LDS, 16B per lane, dest = wave-uniform base + lane*16
__device__ __forceinline__ void gload_lds16(const void* g, void* l) {
  __builtin_amdgcn_global_load_lds((gvoid*)g, (lvoid*)l, 16, 0, 0);
}

__device__ __forceinline__ f32x4 mfma16(bf16x8 a, bf16x8 b, f32x4 c) {
  return __builtin_amdgcn_mfma_f32_16x16x32_bf16(a, b, c, 0, 0, 0);
}

// 64-col bf16 tile: logical (row, col-elem ce) -> swizzled element index.
__device__ __forceinline__ int swz64(int row, int ce) {
  return row * 64 + ((((ce >> 3) ^ (row & 7)) << 3) | (ce & 7));
}

// ---------------------------------------------------------------------------
// LayerNorm (torch variant: unbiased std ddof=1, eps added to std) for the 3
// streams; writes bf16 (GEMM operand) and, for v, also f32 (exact residual).
// grid (4096, 3), block 256, one row per block.
// ---------------------------------------------------------------------------
__global__ __launch_bounds__(256) void ln3_kernel(
    const float* __restrict__ kin, const float* __restrict__ qin,
    const float* __restrict__ vin,
    const float* __restrict__ a2, const float* __restrict__ b2,
    __hip_bfloat16* __restrict__ kn, __hip_bfloat16* __restrict__ qn,
    __hip_bfloat16* __restrict__ vnb, float* __restrict__ vnf)
{
  const int row = blockIdx.x;
  const int st  = blockIdx.y;
  const float* src = (st == 0) ? kin : (st == 1) ? qin : vin;
  const int t = threadIdx.x;
  const size_t base = (size_t)row * D_;

  float4 x = *(const float4*)(src + base + t * 4);
  float s  = x.x + x.y + x.z + x.w;
  float s2 = x.x * x.x + x.y * x.y + x.z * x.z + x.w * x.w;
  #pragma unroll
  for (int off = 32; off >= 1; off >>= 1) {
    s  += __shfl_down(s,  off, 64);
    s2 += __shfl_down(s2, off, 64);
  }
  __shared__ float red[4][2];
  __shared__ float stats[2];
  const int wid = t >> 6, lane = t & 63;
  if (lane == 0) { red[wid][0] = s; red[wid][1] = s2; }
  __syncthreads();
  if (t == 0) {
    float S  = red[0][0] + red[1][0] + red[2][0] + red[3][0];
    float S2 = red[0][1] + red[1][1] + red[2][1] + red[3][1];
    float mean = S * (1.0f / D_);
    float var  = fmaxf((S2 - S * mean) * (1.0f / (D_ - 1)), 0.0f);
    stats[0] = mean;
    stats[1] = 1.0f / (sqrtf(var) + 1e-6f);   // eps added to std
  }
  __syncthreads();
  const float mean = stats[0], inv = stats[1];
  float4 ga = *(const float4*)(a2 + t * 4);
  float4 gb = *(const float4*)(b2 + t * 4);
  float o0 = ga.x * (x.x - mean) * inv + gb.x;
  float o1 = ga.y * (x.y - mean) * inv + gb.y;
  float o2 = ga.z * (x.z - mean) * inv + gb.z;
  float o3 = ga.w * (x.w - mean) * inv + gb.w;
  __hip_bfloat16* dst = (st == 0) ? kn : (st == 1) ? qn : vnb;
  union { __hip_bfloat16 h[4]; ushort4 u; } pk;
  pk.h[0] = __float2bfloat16(o0); pk.h[1] = __float2bfloat16(o1);
  pk.h[2] = __float2bfloat16(o2); pk.h[3] = __float2bfloat16(o3);
  *reinterpret_cast<ushort4*>((unsigned short*)dst + base + t * 4) = pk.u;
  if (st == 2) {
    float4 of = make_float4(o0, o1, o2, o3);
    *reinterpret_cast<float4*>(vnf + base + t * 4) = of;
  }
}

// ---------------------------------------------------------------------------
// Pack mask int32[B,S,S] -> bits u32[B,S,S/32]. grid 1024, block 256.
// ---------------------------------------------------------------------------
__global__ __launch_bounds__(256) void pack_mask_kernel(
    const int* __restrict__ mask, unsigned int* __restrict__ bits)
{
  const int w = blockIdx.x * 256 + threadIdx.x;     // B*S*(S/32) = 262144
  const int* src = mask + (size_t)w * 32;
  unsigned int acc = 0;
  #pragma unroll
  for (int j = 0; j < 32; j += 4) {
    int4 t = *(const int4*)(src + j);
    acc |= (t.x != 0 ? 1u : 0u) << (j + 0);
    acc |= (t.y != 0 ? 1u : 0u) << (j + 1);
    acc |= (t.z != 0 ? 1u : 0u) << (j + 2);
    acc |= (t.w != 0 ? 1u : 0u) << (j + 3);
  }
  bits[w] = acc;
}

// ---------------------------------------------------------------------------
// Weight transpose + cast: W f32[K][N] -> Wt bf16[N][K]. grid (32,32,4).
// ---------------------------------------------------------------------------
__global__ __launch_bounds__(256) void wt_cast_kernel(
    const float* __restrict__ W0, const float* __restrict__ W1,
    const float* __restrict__ W2, const float* __restrict__ W3,
    __hip_bfloat16* __restrict__ T0, __hip_bfloat16* __restrict__ T1,
    __hip_bfloat16* __restrict__ T2, __hip_bfloat16* __restrict__ T3)
{
  const int z = blockIdx.z;
  const float* W = (z == 0) ? W0 : (z == 1) ? W1 : (z == 2) ? W2 : W3;
  __hip_bfloat16* T = (z == 0) ? T0 : (z == 1) ? T1 : (z == 2) ? T2 : T3;
  __shared__ float tile[32][33];
  const int k0 = blockIdx.y * 32, n0 = blockIdx.x * 32;
  const int tx = threadIdx.x & 31, ty = threadIdx.x >> 5;
  #pragma unroll
  for (int i = ty; i < 32; i += 8)
    tile[i][tx] = W[(size_t)(k0 + i) * D_ + n0 + tx];
  __syncthreads();
  #pragma unroll
  for (int i = ty; i < 32; i += 8)
    T[(size_t)(n0 + i) * D_ + k0 + tx] = __float2bfloat16(tile[tx][i]);
}

// ---------------------------------------------------------------------------
// Batched projection GEMM: z=0: Qb=(LN(k)@Wq+bq)*0.125*log2(e) -> [B,H,S,DK]
//                          z=1: Kb= LN(q)@Wk+bk               -> [B,H,S,DK]
//                          z=2: Vtb=LN(v)@Wv+bv               -> [B,H,DK,S]
// 128x128 tile, BK=32, 4 waves (2x2). grid (8, 32, 3), block 256.
// ---------------------------------------------------------------------------
__global__ __launch_bounds__(256) void proj3_kernel(
    const __hip_bfloat16* __restrict__ kn, const __hip_bfloat16* __restrict__ qn,
    const __hip_bfloat16* __restrict__ vnb,
    const __hip_bfloat16* __restrict__ Wqt, const __hip_bfloat16* __restrict__ Wkt,
    const __hip_bfloat16* __restrict__ Wvt,
    const float* __restrict__ bq, const float* __restrict__ bk,
    const float* __restrict__ bv,
    __hip_bfloat16* __restrict__ Qb, __hip_bfloat16* __restrict__ Kb,
    __hip_bfloat16* __restrict__ Vtb)
{
  const int z = blockIdx.z;
  const __hip_bfloat16* A  = (z == 0) ? kn  : (z == 1) ? qn  : vnb;
  const __hip_bfloat16* Wt = (z == 0) ? Wqt : (z == 1) ? Wkt : Wvt;
  const float* bias = (z == 0) ? bq : (z == 1) ? bk : bv;
  // fold 1/sqrt(dk) AND log2(e) into Q so attn softmax uses exp2 directly
  const float scale = (z == 0) ? 0.125f * 1.44269504088896340736f : 1.0f;

  __shared__ __hip_bfloat16 As[128 * 32];
  __shared__ __hip_bfloat16 Bs[128 * 32];
  const int n0 = blockIdx.x * 128;
  const int m0 = blockIdx.y * 128;
  const int tid = threadIdx.x;
  const int wid = tid >> 6, lane = tid & 63;
  const int wm = wid >> 1, wn = wid & 1;
  const int srow = lane >> 2;            // staging: 4 lanes per 64B row
  const int scol = (lane & 3) * 8;
  const int fr = lane & 15, fk8 = (lane >> 4) * 8, fq = lane >> 4;

  f32x4 acc[4][4] = {};

  for (int kt = 0; kt < D_ / 32; ++kt) {
    const int k0 = kt * 32;
    #pragma unroll
    for (int p = 0; p < 2; ++p) {
      const int r0 = 32 * wid + 16 * p;
      gload_lds16(A  + (size_t)(m0 + r0 + srow) * D_ + k0 + scol, &As[r0 * 32]);
      gload_lds16(Wt + (size_t)(n0 + r0 + srow) * D_ + k0 + scol, &Bs[r0 * 32]);
    }
    __syncthreads();
    bf16x8 af[4], bfr[4];
    #pragma unroll
    for (int i = 0; i < 4; ++i)
      af[i] = *(const bf16x8*)&As[(64 * wm + 16 * i + fr) * 32 + fk8];
    #pragma unroll
    for (int j = 0; j < 4; ++j)
      bfr[j] = *(const bf16x8*)&Bs[(64 * wn + 16 * j + fr) * 32 + fk8];
    #pragma unroll
    for (int i = 0; i < 4; ++i)
      #pragma unroll
      for (int j = 0; j < 4; ++j)
        acc[i][j] = mfma16(af[i], bfr[j], acc[i][j]);
    __syncthreads();
  }

  // Epilogue. row m = m0+64*wm+16*i+4*fq+r, col n = n0+64*wn+16*j+fr
  #pragma unroll
  for (int i = 0; i < 4; ++i) {
    #pragma unroll
    for (int j = 0; j < 4; ++j) {
      const int n = n0 + 64 * wn + 16 * j + fr;
      const float bn = bias[n];
      const int h = n >> 6, d = n & (DK_ - 1);
      #pragma unroll
      for (int r = 0; r < 4; ++r) {
        const int m = m0 + 64 * wm + 16 * i + 4 * fq + r;
        const int b = m >> 11, sl = m & (S_ - 1);
        const float val = (acc[i][j][r] + bn) * scale;
        if (z < 2) {
          __hip_bfloat16* dst = (z == 0) ? Qb : Kb;
          dst[((size_t)(b * H_ + h) * S_ + sl) * DK_ + d] = __float2bfloat16(val);
        } else {
          Vtb[((size_t)(b * H_ + h) * DK_ + d) * S_ + sl] = __float2bfloat16(val);
        }
      }
    }
  }
}

// ---------------------------------------------------------------------------
// Output GEMM: out f32[M][D] = Ob @ Wot^T + bo + vnf. grid (8, 32), block 256.
// ---------------------------------------------------------------------------
__global__ __launch_bounds__(256) void gemm_out_kernel(
    const __hip_bfloat16* __restrict__ A,
    const __hip_bfloat16* __restrict__ Wt,
    const float* __restrict__ bias,
    const float* __restrict__ residf,
    float* __restrict__ dst)
{
  __shared__ __hip_bfloat16 As[128 * 32];
  __shared__ __hip_bfloat16 Bs[128 * 32];
  const int n0 = blockIdx.x * 128;
  const int m0 = blockIdx.y * 128;
  const int tid = threadIdx.x;
  const int wid = tid >> 6, lane = tid & 63;
  const int wm = wid >> 1, wn = wid & 1;
  const int srow = lane >> 2;
  const int scol = (lane & 3) * 8;
  const int fr = lane & 15, fk8 = (lane >> 4) * 8, fq = lane >> 4;

  f32x4 acc[4][4] = {};

  for (int kt = 0; kt < D_ / 32; ++kt) {
    const int k0 = kt * 32;
    #pragma unroll
    for (int p = 0; p < 2; ++p) {
      const int r0 = 32 * wid + 16 * p;
      gload_lds16(A  + (size_t)(m0 + r0 + srow) * D_ + k0 + scol, &As[r0 * 32]);
      gload_lds16(Wt + (size_t)(n0 + r0 + srow) * D_ + k0 + scol, &Bs[r0 * 32]);
    }
    __syncthreads();
    bf16x8 af[4], bfr[4];
    #pragma unroll
    for (int i = 0; i < 4; ++i)
      af[i] = *(const bf16x8*)&As[(64 * wm + 16 * i + fr) * 32 + fk8];
    #pragma unroll
    for (int j = 0; j < 4; ++j)
      bfr[j] = *(const bf16x8*)&Bs[(64 * wn + 16 * j + fr) * 32 + fk8];
    #pragma unroll
    for (int i = 0; i < 4; ++i)
      #pragma unroll
      for (int j = 0; j < 4; ++j)
        acc[i][j] = mfma16(af[i], bfr[j], acc[i][j]);
    __syncthreads();
  }

  #pragma unroll
  for (int i = 0; i < 4; ++i) {
    #pragma unroll
    for (int j = 0; j < 4; ++j) {
      const int n = n0 + 64 * wn + 16 * j + fr;
      const float bn = bias[n];
      #pragma unroll
      for (int r = 0; r < 4; ++r) {
        const int m = m0 + 64 * wm + 16 * i + 4 * fq + r;
        dst[(size_t)m * D_ + n] =
            acc[i][j][r] + bn + residf[(size_t)m * D_ + n];
      }
    }
  }
}

// ---------------------------------------------------------------------------
// Flash attention, double-buffered LDS staging (T3-minimal 2-phase): issue
// global_load_lds for tile t+1 into buf^1 BEFORE computing tile t; the single
// end-of-iteration barrier (vmcnt drain) then overlaps stage latency with
// QK^T+softmax+PV. Round-9 lesson: direct global->VGPR fragments are
// latency-bound (no cross-iter prefetch chain) -- LDS staging + dbuf is right.
// Q fragments in registers (loaded once). Fixed-shift softmax: p = exp2(s),
// scale*log2e folded into Q. LDS = 2*8K(K) + 2*8K(V) + 8K(P) = 40 KB ->
// exactly 4 blocks/CU = grid/CU. grid (32, 32), block 256.
// ---------------------------------------------------------------------------
__global__ __launch_bounds__(256) void attn_kernel(
    const __hip_bfloat16* __restrict__ Qb,   // [B,H,S,DK], pre-scaled
    const __hip_bfloat16* __restrict__ Kb,   // [B,H,S,DK]
    const __hip_bfloat16* __restrict__ Vtb,  // [B,H,DK,S]
    const unsigned int* __restrict__ mbits,  // [B,S,S/32]
    __hip_bfloat16* __restrict__ Ob)         // [B,S,D] row-major
{
  __shared__ __hip_bfloat16 Ks[2][64 * 64];
  __shared__ __hip_bfloat16 Vs[2][64 * 64];  // Vs[.][d][kloc]
  __shared__ __hip_bfloat16 Ps[4][16 * 64];  // per-wave P, swizzled

  const int q0 = blockIdx.x * 64;
  const int bh = blockIdx.y;
  const int b = bh >> 4;
  const int h = bh & 15;
  const int tid = threadIdx.x, wid = tid >> 6, lane = tid & 63;
  const __hip_bfloat16* qp = Qb  + (size_t)bh * S_ * DK_;
  const __hip_bfloat16* kp = Kb  + (size_t)bh * S_ * DK_;
  const __hip_bfloat16* vp = Vtb + (size_t)bh * DK_ * S_;

  const int srow = lane >> 3;                       // 8 lanes per 128B row
  const int scol = ((lane & 7) ^ (lane >> 3)) << 3; // inverse-swizzled source
  const int fr = lane & 15, fq = lane >> 4, fk8 = fq * 8;

  // per-lane mask base: rows q0 + 16*wid + 4*fq + r
  const unsigned int* mrow = mbits + (size_t)b * S_ * (S_ / 32)
                           + (size_t)(q0 + 16 * wid + 4 * fq) * (S_ / 32);

  // Q fragments in registers, loaded once (one-time latency, then reg-resident)
  bf16x8 aq[2];
  #pragma unroll
  for (int ks = 0; ks < 2; ++ks)
    aq[ks] = *(const bf16x8*)(qp + (size_t)(q0 + 16 * wid + fr) * DK_
                                 + ks * 32 + fk8);

  auto stage = [&](int kt, int buf) {
    const int k0 = kt * 64;
    #pragma unroll
    for (int p = 0; p < 2; ++p) {
      const int r0 = 16 * wid + 8 * p;
      gload_lds16(kp + (size_t)(k0 + r0 + srow) * DK_ + scol, &Ks[buf][r0 * 64]);
      gload_lds16(vp + (size_t)(r0 + srow) * S_ + k0 + scol,  &Vs[buf][r0 * 64]);
    }
  };

  float lrun[4] = {0.0f, 0.0f, 0.0f, 0.0f};
  f32x4 acc[4] = {};

  stage(0, 0);
  __syncthreads();  // drain prologue stage

  int cur = 0;
  for (int kt = 0; kt < S_ / 64; ++kt) {
    // ---- prefetch next tile into the other buffer (hidden under compute)
    if (kt + 1 < S_ / 64) stage(kt + 1, cur ^ 1);

    // ---- QK^T from Ks[cur] (scale+log2e pre-folded into Q)
    f32x4 sf[4] = {};
    __builtin_amdgcn_s_setprio(1);
    #pragma unroll
    for (int ks = 0; ks < 2; ++ks) {
      #pragma unroll
      for (int ni = 0; ni < 4; ++ni) {
        const bf16x8 bk =
            *(const bf16x8*)&Ks[cur][swz64(16 * ni + fr, ks * 32 + fk8)];
        sf[ni] = mfma16(aq[ks], bk, sf[ni]);
      }
    }
    __builtin_amdgcn_s_setprio(0);

    // ---- mask + exp2 (fixed shift m=0) + lane-local sum + P write
    // D-layout: col = 16*ni + fr, row = 4*fq + r
    unsigned int wm0[4], wm1[4];
    #pragma unroll
    for (int r = 0; r < 4; ++r) {
      wm0[r] = mrow[(size_t)r * (S_ / 32) + 2 * kt];
      wm1[r] = mrow[(size_t)r * (S_ / 32) + 2 * kt + 1];
    }
    #pragma unroll
    for (int ni = 0; ni < 4; ++ni) {
      const int c = 16 * ni + fr;
      #pragma unroll
      for (int r = 0; r < 4; ++r) {
        float p = exp2f(sf[ni][r]);
        const unsigned int bit = (((c < 32) ? wm0[r] : wm1[r]) >> (c & 31)) & 1u;
        p = bit ? p : 0.0f;
        lrun[r] += p;
        Ps[wid][swz64(4 * fq + r, c)] = __float2bfloat16(p);
      }
    }

    // ---- PV from Vs[cur]: acc[q][d] += P[q][kloc] V[kloc][d]
    __builtin_amdgcn_s_setprio(1);
    #pragma unroll
    for (int ks = 0; ks < 2; ++ks) {
      const bf16x8 ap = *(const bf16x8*)&Ps[wid][swz64(fr, ks * 32 + fk8)];
      #pragma unroll
      for (int di = 0; di < 4; ++di) {
        const bf16x8 bv =
            *(const bf16x8*)&Vs[cur][swz64(16 * di + fr, ks * 32 + fk8)];
        acc[di] = mfma16(ap, bv, acc[di]);
      }
    }
    __builtin_amdgcn_s_setprio(0);

    __syncthreads();  // drains next-tile stage; protects buf cur^1 for reuse
    cur ^= 1;
  }

  // ---- epilogue: reduce row-sums across the 16 fr lanes, then O = acc / l
  #pragma unroll
  for (int off = 1; off < 16; off <<= 1)
    #pragma unroll
    for (int r = 0; r < 4; ++r)
      lrun[r] += __shfl_xor(lrun[r], off, 64);

  #pragma unroll
  for (int di = 0; di < 4; ++di)
    #pragma unroll
    for (int r = 0; r < 4; ++r) {
      const int qg = q0 + 16 * wid + 4 * fq + r;
      Ob[((size_t)b * S_ + qg) * D_ + h * DK_ + 16 * di + fr] =
          __float2bfloat16(acc[di][r] / lrun[r]);
    }
}

// ---------------------------------------------------------------------------
extern "C" void kernel_launch(void* const* d_in, const int* in_sizes, int n_in,
                              void* d_out, int out_size, void* d_ws, size_t ws_size,
                              hipStream_t stream)
{
  const float* k    = (const float*)d_in[0];
  const float* q    = (const float*)d_in[1];
  const float* v    = (const float*)d_in[2];
  const int*   mask = (const int*)  d_in[3];
  const float* Wq   = (const float*)d_in[4];
  const float* bq   = (const float*)d_in[5];
  const float* Wk   = (const float*)d_in[6];
  const float* bk   = (const float*)d_in[7];
  const float* Wv   = (const float*)d_in[8];
  const float* bv   = (const float*)d_in[9];
  const float* Wo   = (const float*)d_in[10];
  const float* bo   = (const float*)d_in[11];
  const float* a2   = (const float*)d_in[12];
  const float* b2   = (const float*)d_in[13];

  char* ws = (char*)d_ws;
  const size_t MB = (size_t)1 << 20;
  __hip_bfloat16* kn   = (__hip_bfloat16*)(ws + 0 * MB);   // 8 MiB  LN(k) bf16
  __hip_bfloat16* qn   = (__hip_bfloat16*)(ws + 8 * MB);   // 8 MiB  LN(q) bf16
  __hip_bfloat16* vnb  = (__hip_bfloat16*)(ws + 16 * MB);  // 8 MiB  LN(v) bf16
  __hip_bfloat16* Wqt  = (__hip_bfloat16*)(ws + 24 * MB);  // 2 MiB
  __hip_bfloat16* Wkt  = (__hip_bfloat16*)(ws + 26 * MB);  // 2 MiB
  __hip_bfloat16* Wvt  = (__hip_bfloat16*)(ws + 28 * MB);  // 2 MiB
  __hip_bfloat16* Wot  = (__hip_bfloat16*)(ws + 30 * MB);  // 2 MiB
  __hip_bfloat16* Qb   = (__hip_bfloat16*)(ws + 32 * MB);  // 8 MiB  [B,H,S,DK]
  __hip_bfloat16* Kb   = (__hip_bfloat16*)(ws + 40 * MB);  // 8 MiB  [B,H,S,DK]
  __hip_bfloat16* Vtb  = (__hip_bfloat16*)(ws + 48 * MB);  // 8 MiB  [B,H,DK,S]
  __hip_bfloat16* Ob   = (__hip_bfloat16*)(ws + 56 * MB);  // 8 MiB  [M,D]
  unsigned int*   mbts = (unsigned int*)  (ws + 64 * MB);  // 2 MiB  mask bits
  float*          vnf  = (float*)         (ws + 66 * MB);  // 16 MiB LN(v) f32

  ln3_kernel<<<dim3(M_, 3), 256, 0, stream>>>(k, q, v, a2, b2, kn, qn, vnb, vnf);
  pack_mask_kernel<<<dim3(B_ * S_ * (S_ / 32) / 256), 256, 0, stream>>>(mask, mbts);
  wt_cast_kernel<<<dim3(32, 32, 4), 256, 0, stream>>>(Wq, Wk, Wv, Wo, Wqt, Wkt, Wvt, Wot);

  // Reference quirk: query = LN(k)@Wq, key = LN(q)@Wk, value = LN(v)@Wv
  proj3_kernel<<<dim3(8, 32, 3), 256, 0, stream>>>(
      kn, qn, vnb, Wqt, Wkt, Wvt, bq, bk, bv, Qb, Kb, Vtb);

  attn_kernel<<<dim3(S_ / 64, B_ * H_), 256, 0, stream>>>(Qb, Kb, Vtb, mbts, Ob);

  gemm_out_kernel<<<dim3(8, 32), 256, 0, stream>>>(Ob, Wot, bo, vnf, (float*)d_out);
}

// Round 13
// 299.371 us; speedup vs baseline: 1.6089x; 1.0874x over previous
//
#include <hip/hip_runtime.h>
#include <hip/hip_bf16.h>

// Problem constants
#define B_  2
#define S_  2048
#define D_  1024
#define H_  16
#define DK_ 64
#define M_  4096   // B_*S_

using bf16x8 = __attribute__((ext_vector_type(8))) __bf16;
using f32x4  = __attribute__((ext_vector_type(4))) float;

typedef __attribute__((address_space(1))) void gvoid;
typedef __attribute__((address_space(3))) void lvoid;

// async global->LDS, 16B per lane, dest = wave-uniform base + lane*16
__device__ __forceinline__ void gload_lds16(const void* g, void* l) {
  __builtin_amdgcn_global_load_lds((gvoid*)g, (lvoid*)l, 16, 0, 0);
}

__device__ __forceinline__ f32x4 mfma16(bf16x8 a, bf16x8 b, f32x4 c) {
  return __builtin_amdgcn_mfma_f32_16x16x32_bf16(a, b, c, 0, 0, 0);
}

// 64-col bf16 tile: logical (row, col-elem ce) -> swizzled element index.
__device__ __forceinline__ int swz64(int row, int ce) {
  return row * 64 + ((((ce >> 3) ^ (row & 7)) << 3) | (ce & 7));
}

// ---------------------------------------------------------------------------
// LayerNorm (torch variant: unbiased std ddof=1, eps added to std) for the 3
// streams; writes bf16 (GEMM operand) and, for v, also f32 (exact residual).
// grid (4096, 3), block 256, one row per block.
// ---------------------------------------------------------------------------
__global__ __launch_bounds__(256) void ln3_kernel(
    const float* __restrict__ kin, const float* __restrict__ qin,
    const float* __restrict__ vin,
    const float* __restrict__ a2, const float* __restrict__ b2,
    __hip_bfloat16* __restrict__ kn, __hip_bfloat16* __restrict__ qn,
    __hip_bfloat16* __restrict__ vnb, float* __restrict__ vnf)
{
  const int row = blockIdx.x;
  const int st  = blockIdx.y;
  const float* src = (st == 0) ? kin : (st == 1) ? qin : vin;
  const int t = threadIdx.x;
  const size_t base = (size_t)row * D_;

  float4 x = *(const float4*)(src + base + t * 4);
  float s  = x.x + x.y + x.z + x.w;
  float s2 = x.x * x.x + x.y * x.y + x.z * x.z + x.w * x.w;
  #pragma unroll
  for (int off = 32; off >= 1; off >>= 1) {
    s  += __shfl_down(s,  off, 64);
    s2 += __shfl_down(s2, off, 64);
  }
  __shared__ float red[4][2];
  __shared__ float stats[2];
  const int wid = t >> 6, lane = t & 63;
  if (lane == 0) { red[wid][0] = s; red[wid][1] = s2; }
  __syncthreads();
  if (t == 0) {
    float S  = red[0][0] + red[1][0] + red[2][0] + red[3][0];
    float S2 = red[0][1] + red[1][1] + red[2][1] + red[3][1];
    float mean = S * (1.0f / D_);
    float var  = fmaxf((S2 - S * mean) * (1.0f / (D_ - 1)), 0.0f);
    stats[0] = mean;
    stats[1] = 1.0f / (sqrtf(var) + 1e-6f);   // eps added to std
  }
  __syncthreads();
  const float mean = stats[0], inv = stats[1];
  float4 ga = *(const float4*)(a2 + t * 4);
  float4 gb = *(const float4*)(b2 + t * 4);
  float o0 = ga.x * (x.x - mean) * inv + gb.x;
  float o1 = ga.y * (x.y - mean) * inv + gb.y;
  float o2 = ga.z * (x.z - mean) * inv + gb.z;
  float o3 = ga.w * (x.w - mean) * inv + gb.w;
  __hip_bfloat16* dst = (st == 0) ? kn : (st == 1) ? qn : vnb;
  union { __hip_bfloat16 h[4]; ushort4 u; } pk;
  pk.h[0] = __float2bfloat16(o0); pk.h[1] = __float2bfloat16(o1);
  pk.h[2] = __float2bfloat16(o2); pk.h[3] = __float2bfloat16(o3);
  *reinterpret_cast<ushort4*>((unsigned short*)dst + base + t * 4) = pk.u;
  if (st == 2) {
    float4 of = make_float4(o0, o1, o2, o3);
    *reinterpret_cast<float4*>(vnf + base + t * 4) = of;
  }
}

// ---------------------------------------------------------------------------
// Pack mask int32[B,S,S] -> bits u32[B,S,S/32]. grid 1024, block 256.
// ---------------------------------------------------------------------------
__global__ __launch_bounds__(256) void pack_mask_kernel(
    const int* __restrict__ mask, unsigned int* __restrict__ bits)
{
  const int w = blockIdx.x * 256 + threadIdx.x;     // B*S*(S/32) = 262144
  const int* src = mask + (size_t)w * 32;
  unsigned int acc = 0;
  #pragma unroll
  for (int j = 0; j < 32; j += 4) {
    int4 t = *(const int4*)(src + j);
    acc |= (t.x != 0 ? 1u : 0u) << (j + 0);
    acc |= (t.y != 0 ? 1u : 0u) << (j + 1);
    acc |= (t.z != 0 ? 1u : 0u) << (j + 2);
    acc |= (t.w != 0 ? 1u : 0u) << (j + 3);
  }
  bits[w] = acc;
}

// ---------------------------------------------------------------------------
// Weight transpose + cast: W f32[K][N] -> Wt bf16[N][K]. grid (32,32,4).
// ---------------------------------------------------------------------------
__global__ __launch_bounds__(256) void wt_cast_kernel(
    const float* __restrict__ W0, const float* __restrict__ W1,
    const float* __restrict__ W2, const float* __restrict__ W3,
    __hip_bfloat16* __restrict__ T0, __hip_bfloat16* __restrict__ T1,
    __hip_bfloat16* __restrict__ T2, __hip_bfloat16* __restrict__ T3)
{
  const int z = blockIdx.z;
  const float* W = (z == 0) ? W0 : (z == 1) ? W1 : (z == 2) ? W2 : W3;
  __hip_bfloat16* T = (z == 0) ? T0 : (z == 1) ? T1 : (z == 2) ? T2 : T3;
  __shared__ float tile[32][33];
  const int k0 = blockIdx.y * 32, n0 = blockIdx.x * 32;
  const int tx = threadIdx.x & 31, ty = threadIdx.x >> 5;
  #pragma unroll
  for (int i = ty; i < 32; i += 8)
    tile[i][tx] = W[(size_t)(k0 + i) * D_ + n0 + tx];
  __syncthreads();
  #pragma unroll
  for (int i = ty; i < 32; i += 8)
    T[(size_t)(n0 + i) * D_ + k0 + tx] = __float2bfloat16(tile[tx][i]);
}

// ---------------------------------------------------------------------------
// Batched projection GEMM: z=0: Qb=(LN(k)@Wq+bq)*0.125 -> [B,H,S,DK]
//                          z=1: Kb= LN(q)@Wk+bk        -> [B,H,S,DK]
//                          z=2: Vtb=LN(v)@Wv+bv        -> [B,H,DK,S] (transposed)
// 128x128 tile, BK=32, 4 waves (2x2). grid (8, 32, 3), block 256.
// ---------------------------------------------------------------------------
__global__ __launch_bounds__(256) void proj3_kernel(
    const __hip_bfloat16* __restrict__ kn, const __hip_bfloat16* __restrict__ qn,
    const __hip_bfloat16* __restrict__ vnb,
    const __hip_bfloat16* __restrict__ Wqt, const __hip_bfloat16* __restrict__ Wkt,
    const __hip_bfloat16* __restrict__ Wvt,
    const float* __restrict__ bq, const float* __restrict__ bk,
    const float* __restrict__ bv,
    __hip_bfloat16* __restrict__ Qb, __hip_bfloat16* __restrict__ Kb,
    __hip_bfloat16* __restrict__ Vtb)
{
  const int z = blockIdx.z;
  const __hip_bfloat16* A  = (z == 0) ? kn  : (z == 1) ? qn  : vnb;
  const __hip_bfloat16* Wt = (z == 0) ? Wqt : (z == 1) ? Wkt : Wvt;
  const float* bias = (z == 0) ? bq : (z == 1) ? bk : bv;
  const float scale = (z == 0) ? 0.125f : 1.0f;   // fold 1/sqrt(dk) into Q

  __shared__ __hip_bfloat16 As[128 * 32];
  __shared__ __hip_bfloat16 Bs[128 * 32];
  const int n0 = blockIdx.x * 128;
  const int m0 = blockIdx.y * 128;
  const int tid = threadIdx.x;
  const int wid = tid >> 6, lane = tid & 63;
  const int wm = wid >> 1, wn = wid & 1;
  const int srow = lane >> 2;            // staging: 4 lanes per 64B row
  const int scol = (lane & 3) * 8;
  const int fr = lane & 15, fk8 = (lane >> 4) * 8, fq = lane >> 4;

  f32x4 acc[4][4] = {};

  for (int kt = 0; kt < D_ / 32; ++kt) {
    const int k0 = kt * 32;
    #pragma unroll
    for (int p = 0; p < 2; ++p) {
      const int r0 = 32 * wid + 16 * p;
      gload_lds16(A  + (size_t)(m0 + r0 + srow) * D_ + k0 + scol, &As[r0 * 32]);
      gload_lds16(Wt + (size_t)(n0 + r0 + srow) * D_ + k0 + scol, &Bs[r0 * 32]);
    }
    __syncthreads();
    bf16x8 af[4], bfr[4];
    #pragma unroll
    for (int i = 0; i < 4; ++i)
      af[i] = *(const bf16x8*)&As[(64 * wm + 16 * i + fr) * 32 + fk8];
    #pragma unroll
    for (int j = 0; j < 4; ++j)
      bfr[j] = *(const bf16x8*)&Bs[(64 * wn + 16 * j + fr) * 32 + fk8];
    #pragma unroll
    for (int i = 0; i < 4; ++i)
      #pragma unroll
      for (int j = 0; j < 4; ++j)
        acc[i][j] = mfma16(af[i], bfr[j], acc[i][j]);
    __syncthreads();
  }

  // Epilogue. row m = m0+64*wm+16*i+4*fq+r, col n = n0+64*wn+16*j+fr
  #pragma unroll
  for (int i = 0; i < 4; ++i) {
    #pragma unroll
    for (int j = 0; j < 4; ++j) {
      const int n = n0 + 64 * wn + 16 * j + fr;
      const float bn = bias[n];
      const int h = n >> 6, d = n & (DK_ - 1);
      #pragma unroll
      for (int r = 0; r < 4; ++r) {
        const int m = m0 + 64 * wm + 16 * i + 4 * fq + r;
        const int b = m >> 11, sl = m & (S_ - 1);
        const float val = (acc[i][j][r] + bn) * scale;
        if (z < 2) {
          __hip_bfloat16* dst = (z == 0) ? Qb : Kb;
          dst[((size_t)(b * H_ + h) * S_ + sl) * DK_ + d] = __float2bfloat16(val);
        } else {
          Vtb[((size_t)(b * H_ + h) * DK_ + d) * S_ + sl] = __float2bfloat16(val);
        }
      }
    }
  }
}

// ---------------------------------------------------------------------------
// Output GEMM: out f32[M][D] = Ob @ Wot^T + bo + vnf. grid (8, 32), block 256.
// ---------------------------------------------------------------------------
__global__ __launch_bounds__(256) void gemm_out_kernel(
    const __hip_bfloat16* __restrict__ A,
    const __hip_bfloat16* __restrict__ Wt,
    const float* __restrict__ bias,
    const float* __restrict__ residf,
    float* __restrict__ dst)
{
  __shared__ __hip_bfloat16 As[128 * 32];
  __shared__ __hip_bfloat16 Bs[128 * 32];
  const int n0 = blockIdx.x * 128;
  const int m0 = blockIdx.y * 128;
  const int tid = threadIdx.x;
  const int wid = tid >> 6, lane = tid & 63;
  const int wm = wid >> 1, wn = wid & 1;
  const int srow = lane >> 2;
  const int scol = (lane & 3) * 8;
  const int fr = lane & 15, fk8 = (lane >> 4) * 8, fq = lane >> 4;

  f32x4 acc[4][4] = {};

  for (int kt = 0; kt < D_ / 32; ++kt) {
    const int k0 = kt * 32;
    #pragma unroll
    for (int p = 0; p < 2; ++p) {
      const int r0 = 32 * wid + 16 * p;
      gload_lds16(A  + (size_t)(m0 + r0 + srow) * D_ + k0 + scol, &As[r0 * 32]);
      gload_lds16(Wt + (size_t)(n0 + r0 + srow) * D_ + k0 + scol, &Bs[r0 * 32]);
    }
    __syncthreads();
    bf16x8 af[4], bfr[4];
    #pragma unroll
    for (int i = 0; i < 4; ++i)
      af[i] = *(const bf16x8*)&As[(64 * wm + 16 * i + fr) * 32 + fk8];
    #pragma unroll
    for (int j = 0; j < 4; ++j)
      bfr[j] = *(const bf16x8*)&Bs[(64 * wn + 16 * j + fr) * 32 + fk8];
    #pragma unroll
    for (int i = 0; i < 4; ++i)
      #pragma unroll
      for (int j = 0; j < 4; ++j)
        acc[i][j] = mfma16(af[i], bfr[j], acc[i][j]);
    __syncthreads();
  }

  #pragma unroll
  for (int i = 0; i < 4; ++i) {
    #pragma unroll
    for (int j = 0; j < 4; ++j) {
      const int n = n0 + 64 * wn + 16 * j + fr;
      const float bn = bias[n];
      #pragma unroll
      for (int r = 0; r < 4; ++r) {
        const int m = m0 + 64 * wm + 16 * i + 4 * fq + r;
        dst[(size_t)m * D_ + n] =
            acc[i][j][r] + bn + residf[(size_t)m * D_ + n];
      }
    }
  }
}

// ---------------------------------------------------------------------------
// Flash attention — REVERT to round-6 measured structure (80.6 us): single-
// buffer LDS staging of K/V per tile, stage -> barrier -> compute -> barrier.
// Round-12 lesson: explicit double-buffer HURT (107.7 us; barrier still drains
// vmcnt(0) per guide m99/m100, and it cost occupancy 36.8->24.7%). Retained
// win: Q fragments in REGISTERS (loaded once; -2 ds_read/iter, LDS 24 KB).
// Fixed-shift softmax: p = __expf(s), masked -> 0; scale 0.125 folded into Q.
// block = (q-tile of 64, b*H+h), 4 waves x 16 q-rows, KVBLK=64. grid (32,32).
// ---------------------------------------------------------------------------
__global__ __launch_bounds__(256) void attn_kernel(
    const __hip_bfloat16* __restrict__ Qb,   // [B,H,S,DK], pre-scaled by 1/8
    const __hip_bfloat16* __restrict__ Kb,   // [B,H,S,DK]
    const __hip_bfloat16* __restrict__ Vtb,  // [B,H,DK,S]
    const unsigned int* __restrict__ mbits,  // [B,S,S/32]
    __hip_bfloat16* __restrict__ Ob)         // [B,S,D] row-major
{
  __shared__ __hip_bfloat16 Ks[64 * 64];
  __shared__ __hip_bfloat16 Vs[64 * 64];     // Vs[d][kloc]
  __shared__ __hip_bfloat16 Ps[4][16 * 64];  // per-wave P, swizzled

  const int q0 = blockIdx.x * 64;
  const int bh = blockIdx.y;
  const int b = bh >> 4;
  const int h = bh & 15;
  const int tid = threadIdx.x, wid = tid >> 6, lane = tid & 63;
  const __hip_bfloat16* qp = Qb  + (size_t)bh * S_ * DK_;
  const __hip_bfloat16* kp = Kb  + (size_t)bh * S_ * DK_;
  const __hip_bfloat16* vp = Vtb + (size_t)bh * DK_ * S_;

  const int srow = lane >> 3;                       // 8 lanes per 128B row
  const int scol = ((lane & 7) ^ (lane >> 3)) << 3; // inverse-swizzled source
  const int fr = lane & 15, fq = lane >> 4, fk8 = fq * 8;

  // per-lane mask base: rows q0 + 16*wid + 4*fq + r
  const unsigned int* mrow = mbits + (size_t)b * S_ * (S_ / 32)
                           + (size_t)(q0 + 16 * wid + 4 * fq) * (S_ / 32);

  // Q fragments in registers, loaded once
  bf16x8 aq[2];
  #pragma unroll
  for (int ks = 0; ks < 2; ++ks)
    aq[ks] = *(const bf16x8*)(qp + (size_t)(q0 + 16 * wid + fr) * DK_
                                 + ks * 32 + fk8);

  float lrun[4] = {0.0f, 0.0f, 0.0f, 0.0f};
  f32x4 acc[4] = {};

  for (int kt = 0; kt < S_ / 64; ++kt) {
    const int k0 = kt * 64;
    // ---- stage K tile [64][64] and Vt tile [64 d][64 kloc], swizzled
    #pragma unroll
    for (int p = 0; p < 2; ++p) {
      const int r0 = 16 * wid + 8 * p;
      gload_lds16(kp + (size_t)(k0 + r0 + srow) * DK_ + scol, &Ks[r0 * 64]);
      gload_lds16(vp + (size_t)(r0 + srow) * S_ + k0 + scol,  &Vs[r0 * 64]);
    }
    __syncthreads();

    // ---- QK^T (scale pre-folded into Q)
    f32x4 sf[4] = {};
    __builtin_amdgcn_s_setprio(1);
    #pragma unroll
    for (int ks = 0; ks < 2; ++ks) {
      #pragma unroll
      for (int ni = 0; ni < 4; ++ni) {
        const bf16x8 bk = *(const bf16x8*)&Ks[swz64(16 * ni + fr, ks * 32 + fk8)];
        sf[ni] = mfma16(aq[ks], bk, sf[ni]);
      }
    }
    __builtin_amdgcn_s_setprio(0);

    // ---- mask + exp (fixed shift m=0) + lane-local sum + P write
    // D-layout: col = 16*ni + fr, row = 4*fq + r
    unsigned int wm0[4], wm1[4];
    #pragma unroll
    for (int r = 0; r < 4; ++r) {
      wm0[r] = mrow[(size_t)r * (S_ / 32) + 2 * kt];
      wm1[r] = mrow[(size_t)r * (S_ / 32) + 2 * kt + 1];
    }
    #pragma unroll
    for (int ni = 0; ni < 4; ++ni) {
      const int c = 16 * ni + fr;
      #pragma unroll
      for (int r = 0; r < 4; ++r) {
        float p = __expf(sf[ni][r]);
        const unsigned int bit = (((c < 32) ? wm0[r] : wm1[r]) >> (c & 31)) & 1u;
        p = bit ? p : 0.0f;
        lrun[r] += p;
        Ps[wid][swz64(4 * fq + r, c)] = __float2bfloat16(p);
      }
    }

    // ---- PV: acc[q][d] += P[q][kloc] V[kloc][d]
    __builtin_amdgcn_s_setprio(1);
    #pragma unroll
    for (int ks = 0; ks < 2; ++ks) {
      const bf16x8 ap = *(const bf16x8*)&Ps[wid][swz64(fr, ks * 32 + fk8)];
      #pragma unroll
      for (int di = 0; di < 4; ++di) {
        const bf16x8 bv = *(const bf16x8*)&Vs[swz64(16 * di + fr, ks * 32 + fk8)];
        acc[di] = mfma16(ap, bv, acc[di]);
      }
    }
    __builtin_amdgcn_s_setprio(0);
    __syncthreads();  // protect Ks/Vs for next iteration
  }

  // ---- epilogue: reduce row-sums across the 16 fr lanes, then O = acc / l
  #pragma unroll
  for (int off = 1; off < 16; off <<= 1)
    #pragma unroll
    for (int r = 0; r < 4; ++r)
      lrun[r] += __shfl_xor(lrun[r], off, 64);

  #pragma unroll
  for (int di = 0; di < 4; ++di)
    #pragma unroll
    for (int r = 0; r < 4; ++r) {
      const int qg = q0 + 16 * wid + 4 * fq + r;
      Ob[((size_t)b * S_ + qg) * D_ + h * DK_ + 16 * di + fr] =
          __float2bfloat16(acc[di][r] / lrun[r]);
    }
}

// ---------------------------------------------------------------------------
extern "C" void kernel_launch(void* const* d_in, const int* in_sizes, int n_in,
                              void* d_out, int out_size, void* d_ws, size_t ws_size,
                              hipStream_t stream)
{
  const float* k    = (const float*)d_in[0];
  const float* q    = (const float*)d_in[1];
  const float* v    = (const float*)d_in[2];
  const int*   mask = (const int*)  d_in[3];
  const float* Wq   = (const float*)d_in[4];
  const float* bq   = (const float*)d_in[5];
  const float* Wk   = (const float*)d_in[6];
  const float* bk   = (const float*)d_in[7];
  const float* Wv   = (const float*)d_in[8];
  const float* bv   = (const float*)d_in[9];
  const float* Wo   = (const float*)d_in[10];
  const float* bo   = (const float*)d_in[11];
  const float* a2   = (const float*)d_in[12];
  const float* b2   = (const float*)d_in[13];

  char* ws = (char*)d_ws;
  const size_t MB = (size_t)1 << 20;
  __hip_bfloat16* kn   = (__hip_bfloat16*)(ws + 0 * MB);   // 8 MiB  LN(k) bf16
  __hip_bfloat16* qn   = (__hip_bfloat16*)(ws + 8 * MB);   // 8 MiB  LN(q) bf16
  __hip_bfloat16* vnb  = (__hip_bfloat16*)(ws + 16 * MB);  // 8 MiB  LN(v) bf16
  __hip_bfloat16* Wqt  = (__hip_bfloat16*)(ws + 24 * MB);  // 2 MiB
  __hip_bfloat16* Wkt  = (__hip_bfloat16*)(ws + 26 * MB);  // 2 MiB
  __hip_bfloat16* Wvt  = (__hip_bfloat16*)(ws + 28 * MB);  // 2 MiB
  __hip_bfloat16* Wot  = (__hip_bfloat16*)(ws + 30 * MB);  // 2 MiB
  __hip_bfloat16* Qb   = (__hip_bfloat16*)(ws + 32 * MB);  // 8 MiB  [B,H,S,DK]
  __hip_bfloat16* Kb   = (__hip_bfloat16*)(ws + 40 * MB);  // 8 MiB  [B,H,S,DK]
  __hip_bfloat16* Vtb  = (__hip_bfloat16*)(ws + 48 * MB);  // 8 MiB  [B,H,DK,S]
  __hip_bfloat16* Ob   = (__hip_bfloat16*)(ws + 56 * MB);  // 8 MiB  [M,D]
  unsigned int*   mbts = (unsigned int*)  (ws + 64 * MB);  // 2 MiB  mask bits
  float*          vnf  = (float*)         (ws + 66 * MB);  // 16 MiB LN(v) f32

  ln3_kernel<<<dim3(M_, 3), 256, 0, stream>>>(k, q, v, a2, b2, kn, qn, vnb, vnf);
  pack_mask_kernel<<<dim3(B_ * S_ * (S_ / 32) / 256), 256, 0, stream>>>(mask, mbts);
  wt_cast_kernel<<<dim3(32, 32, 4), 256, 0, stream>>>(Wq, Wk, Wv, Wo, Wqt, Wkt, Wvt, Wot);

  // Reference quirk: query = LN(k)@Wq, key = LN(q)@Wk, value = LN(v)@Wv
  proj3_kernel<<<dim3(8, 32, 3), 256, 0, stream>>>(
      kn, qn, vnb, Wqt, Wkt, Wvt, bq, bk, bv, Qb, Kb, Vtb);

  attn_kernel<<<dim3(S_ / 64, B_ * H_), 256, 0, stream>>>(Qb, Kb, Vtb, mbts, Ob);

  gemm_out_kernel<<<dim3(8, 32), 256, 0, stream>>>(Ob, Wot, bo, vnf, (float*)d_out);
}